// Round 1
// baseline (1016.856 us; speedup 1.0000x reference)
//
#include <hip/hip_runtime.h>

// Grid constants (match the JAX reference)
#define NX   480
#define NXC  960
#define NS   (480*480)     // 230400 spatial cells (direct / pooled grids)
#define NSC  (960*960)     // 921600 spatial cells ('cen' grids)
#define CC   64            // channels per source
#define BB   2             // batch

typedef float f4v __attribute__((ext_vector_type(4)));

__device__ __forceinline__ f4v max4(f4v a, f4v b) {
    f4v r;
    r.x = fmaxf(a.x, b.x); r.y = fmaxf(a.y, b.y);
    r.z = fmaxf(a.z, b.z); r.w = fmaxf(a.w, b.w);
    return r;
}

// ---------------------------------------------------------------------------
// Pass 1: winner resolution — last point index wins (atomicMax on p).
// All four sources in one dispatch (blockIdx.y selects the source).
// Cen sources additionally resolve a POOLED winner at output-cell (480x480)
// granularity: the max-index point among all points mapping to an output
// cell becomes that cell's unique "representative" for the sparse pass.
// ---------------------------------------------------------------------------
struct SrcDesc { const int* coords; int* winner; int* pooled; int P; int nx; int ns; };

__global__ void __launch_bounds__(256)
scatter_winner4(SrcDesc s0, SrcDesc s1, SrcDesc s2, SrcDesc s3) {
    SrcDesc d = (blockIdx.y == 0) ? s0 : (blockIdx.y == 1) ? s1
              : (blockIdx.y == 2) ? s2 : s3;
    int p = blockIdx.x * 256 + threadIdx.x;
    if (p >= d.P) return;
    int b = d.coords[4*p + 0];
    int y = d.coords[4*p + 2];
    int x = d.coords[4*p + 3];
    atomicMax(&d.winner[b*d.ns + y*d.nx + x], p);
    if (d.pooled)   // wave-uniform branch (per blockIdx.y)
        atomicMax(&d.pooled[b*NS + (y>>1)*NX + (x>>1)], p);
}

// ---------------------------------------------------------------------------
// Pass 2 (sparse): outputs were zero-filled by memset at fill-rate; only the
// ~6% occupied cells are written here. Thread = (point p, channel-quad q).
// Lanes 0..15 of a 16-lane group read point p's feature row fully coalesced
// (256B). Stores are scattered 4B (channel planes stride NS), non-temporal so
// they bypass L2 (no write-allocate RMW) and go out as masked HBM bursts.
//  job 0: lidar      -> out_l  + cat[  0.. 63]
//  job 1: radar      -> out_r  + cat[128..191]
//  job 2: lidar_cen  -> 2x2 max-pool (max with 0, matching reference) -> cat[ 64..127]
//  job 3: radar_cen  -> cat[192..255]
// Only the unique pooled-winner representative thread-group writes a cen cell.
// ---------------------------------------------------------------------------
__global__ void __launch_bounds__(256)
sparse_write(const float* __restrict__ lf,  const float* __restrict__ rf,
             const float* __restrict__ lcf, const float* __restrict__ rcf,
             const int* __restrict__ l_coords,  const int* __restrict__ r_coords,
             const int* __restrict__ lc_coords, const int* __restrict__ rc_coords,
             const int* __restrict__ wl,  const int* __restrict__ wr,
             const int* __restrict__ wlc, const int* __restrict__ wrc,
             const int* __restrict__ wplc, const int* __restrict__ wprc,
             int P_l, int P_r, int P_lc, int P_rc,
             float* __restrict__ out_l, float* __restrict__ out_r,
             float* __restrict__ out_cat)
{
    int idx = blockIdx.x * 256 + threadIdx.x;
    int p = idx >> 4;          // point index
    int q = idx & 15;          // channel quad (4*q .. 4*q+3)
    int job = blockIdx.y;

    if (job < 2) {
        // --- direct grids: copy winner row to out_{l,r} and cat ---
        const float* f      = job ? rf       : lf;
        const int*   coords = job ? r_coords : l_coords;
        const int*   w      = job ? wr       : wl;
        int          P      = job ? P_r      : P_l;
        if (p >= P) return;
        int4 c = *(const int4*)(coords + 4*p);
        int b  = c.x;
        int sp = c.z * NX + c.w;
        if (w[b*NS + sp] != p) return;          // not this cell's winner
        f4v v = *(const f4v*)(f + (size_t)p*CC + 4*q);
        float* o1 = (job ? out_r : out_l)
                  + (size_t)b*CC*NS  + (size_t)(4*q)*NS + sp;
        float* o2 = out_cat
                  + (size_t)b*256*NS + (size_t)((job ? 128 : 0) + 4*q)*NS + sp;
        #pragma unroll
        for (int k = 0; k < 4; ++k) {
            __builtin_nontemporal_store(v[k], o1 + (size_t)k*NS);
            __builtin_nontemporal_store(v[k], o2 + (size_t)k*NS);
        }
    } else {
        // --- cen grids: 2x2 max-pool of sub-cell winner rows -> cat ---
        const float* f      = (job == 3) ? rcf       : lcf;
        const int*   coords = (job == 3) ? rc_coords : lc_coords;
        const int*   w      = (job == 3) ? wrc       : wlc;
        const int*   wp     = (job == 3) ? wprc      : wplc;
        int          P      = (job == 3) ? P_rc      : P_lc;
        if (p >= P) return;
        int4 c = *(const int4*)(coords + 4*p);
        int b  = c.x;
        int oy = c.z >> 1, ox = c.w >> 1;
        int o  = oy * NX + ox;
        if (wp[b*NS + o] != p) return;          // not this out-cell's representative
        const int* wg = w + (size_t)b*NSC + (size_t)(oy*2)*NXC + ox*2;
        int w00 = wg[0], w01 = wg[1], w10 = wg[NXC], w11 = wg[NXC + 1];
        f4v a = {0.0f, 0.0f, 0.0f, 0.0f};       // maxpool over zero-init grid => max with 0
        if (w00 >= 0) a = max4(a, *(const f4v*)(f + (size_t)w00*CC + 4*q));
        if (w01 >= 0) a = max4(a, *(const f4v*)(f + (size_t)w01*CC + 4*q));
        if (w10 >= 0) a = max4(a, *(const f4v*)(f + (size_t)w10*CC + 4*q));
        if (w11 >= 0) a = max4(a, *(const f4v*)(f + (size_t)w11*CC + 4*q));
        float* o2 = out_cat
                  + (size_t)b*256*NS + (size_t)((job == 3 ? 192 : 64) + 4*q)*NS + o;
        #pragma unroll
        for (int k = 0; k < 4; ++k)
            __builtin_nontemporal_store(a[k], o2 + (size_t)k*NS);
    }
}

extern "C" void kernel_launch(void* const* d_in, const int* in_sizes, int n_in,
                              void* d_out, int out_size, void* d_ws, size_t ws_size,
                              hipStream_t stream) {
    // Inputs per setup_inputs() order
    const float* rc_feat   = (const float*)d_in[0];  // radar_cen
    const int*   rc_coords = (const int*)  d_in[1];
    const float* lc_feat   = (const float*)d_in[2];  // lidar_cen
    const int*   lc_coords = (const int*)  d_in[3];
    const float* l_feat    = (const float*)d_in[4];  // lidar
    const int*   l_coords  = (const int*)  d_in[5];
    const float* r_feat    = (const float*)d_in[6];  // radar
    const int*   r_coords  = (const int*)  d_in[7];

    int P_rc = in_sizes[0] / CC;
    int P_lc = in_sizes[2] / CC;
    int P_l  = in_sizes[4] / CC;
    int P_r  = in_sizes[6] / CC;

    // Output layout (flat, in return order): lidar, radar, cat
    float* out_lidar = (float*)d_out;                 // [2,64,480,480]
    float* out_radar = out_lidar + (size_t)BB*CC*NS;  // [2,64,480,480]
    float* out_cat   = out_radar + (size_t)BB*CC*NS;  // [2,256,480,480]

    // Workspace: winner grids + pooled-winner grids, init -1 (memset 0xFF)
    int* w_l   = (int*)d_ws;                 // [B*NS]   direct lidar winners
    int* w_r   = w_l   + (size_t)BB*NS;      // [B*NS]   direct radar winners
    int* w_plc = w_r   + (size_t)BB*NS;      // [B*NS]   pooled lidar_cen representative
    int* w_prc = w_plc + (size_t)BB*NS;      // [B*NS]   pooled radar_cen representative
    int* w_lc  = w_prc + (size_t)BB*NS;      // [B*NSC]  lidar_cen sub-cell winners
    int* w_rc  = w_lc  + (size_t)BB*NSC;     // [B*NSC]  radar_cen sub-cell winners
    size_t ws_bytes = ((size_t)4*BB*NS + (size_t)2*BB*NSC) * sizeof(int);  // ~22.1 MB

    hipMemsetAsync(d_ws, 0xFF, ws_bytes, stream);

    // Zero-fill ALL outputs at fill-rate (~6.3 TB/s measured on this chip).
    // 94% of output cells are zero; this replaces the dense gather-write's
    // zero stream with the fastest possible writer.
    size_t out_bytes = (size_t)BB * NS * (2*CC + 256) * sizeof(float);  // 708 MB
    hipMemsetAsync(d_out, 0, out_bytes, stream);

    // Pass 1: winner resolution (+ pooled representative for cen sources)
    SrcDesc s_l  = { l_coords,  w_l,  nullptr, P_l,  NX,  NS  };
    SrcDesc s_r  = { r_coords,  w_r,  nullptr, P_r,  NX,  NS  };
    SrcDesc s_lc = { lc_coords, w_lc, w_plc,   P_lc, NXC, NSC };
    SrcDesc s_rc = { rc_coords, w_rc, w_prc,   P_rc, NXC, NSC };
    int maxP = max(max(P_l, P_r), max(P_lc, P_rc));
    dim3 wgrid((maxP + 255) / 256, 4);
    scatter_winner4<<<wgrid, 256, 0, stream>>>(s_l, s_r, s_lc, s_rc);

    // Pass 2: sparse writes of occupied cells only (~28 MB useful)
    dim3 sgrid((maxP * 16 + 255) / 256, 4);
    sparse_write<<<sgrid, 256, 0, stream>>>(
        l_feat, r_feat, lc_feat, rc_feat,
        l_coords, r_coords, lc_coords, rc_coords,
        w_l, w_r, w_lc, w_rc, w_plc, w_prc,
        P_l, P_r, P_lc, P_rc,
        out_lidar, out_radar, out_cat);
}

// Round 2
// 741.926 us; speedup vs baseline: 1.3706x; 1.3706x over previous
//
#include <hip/hip_runtime.h>

// Grid constants (match the JAX reference)
#define NX   480
#define NXC  960
#define NS   (480*480)     // 230400 spatial cells (direct / pooled grids)
#define NSC  (960*960)     // 921600 spatial cells ('cen' grids)
#define CC   64            // channels per source
#define BB   2             // batch

typedef float f4v __attribute__((ext_vector_type(4)));

__device__ __forceinline__ void nt_store4(float* p, float a, float b, float c, float d) {
    f4v v = {a, b, c, d};
    __builtin_nontemporal_store(v, (f4v*)p);
}

// Gather 4 consecutive channels of winner w's feature row (0-vector if empty).
__device__ __forceinline__ f4v ld4(int w, const float* __restrict__ f, int c) {
    f4v z = {0.0f, 0.0f, 0.0f, 0.0f};
    if (w < 0) return z;                       // exec-mask predicated
    return *(const f4v*)(f + (size_t)w * CC + c);
}

__device__ __forceinline__ f4v max4(f4v a, f4v b) {
    f4v r;
    r.x = fmaxf(a.x, b.x); r.y = fmaxf(a.y, b.y);
    r.z = fmaxf(a.z, b.z); r.w = fmaxf(a.w, b.w);
    return r;
}

// ---------------------------------------------------------------------------
// Pass 1: winner resolution — last point index wins (atomicMax on p).
// All four sources in one dispatch (blockIdx.y selects the source).
// ---------------------------------------------------------------------------
struct SrcDesc { const int* coords; int* winner; int P; int nx; int ns; };

__global__ void __launch_bounds__(256)
scatter_winner4(SrcDesc s0, SrcDesc s1, SrcDesc s2, SrcDesc s3) {
    SrcDesc d = (blockIdx.y == 0) ? s0 : (blockIdx.y == 1) ? s1
              : (blockIdx.y == 2) ? s2 : s3;
    int p = blockIdx.x * 256 + threadIdx.x;
    if (p >= d.P) return;
    int b = d.coords[4*p + 0];
    int y = d.coords[4*p + 2];
    int x = d.coords[4*p + 3];
    atomicMax(&d.winner[b*d.ns + y*d.nx + x], p);
}

// ---------------------------------------------------------------------------
// Pass 2a: direct grids (lidar, radar). Thread owns 4 consecutive cells x all
// 64 channels of ONE source (blockIdx.z). Low VGPR (winners:4 + one gather
// group in flight) -> high occupancy; each winner's 256B feature row is
// consumed sequentially by one thread (L1 line reuse). Stores are coalesced
// 16B nt (wave covers 1KB per store inst). Writes out_{l,r} AND the matching
// cat section, so every output byte is written exactly once, no memset.
// ---------------------------------------------------------------------------
__global__ void __launch_bounds__(256)
dense_direct(const float* __restrict__ lf, const float* __restrict__ rf,
             const int* __restrict__ wl, const int* __restrict__ wr,
             float* __restrict__ out_l, float* __restrict__ out_r,
             float* __restrict__ out_cat)
{
    int s = (blockIdx.x * 256 + threadIdx.x) * 4;   // first of 4 cells
    int b = blockIdx.y;
    int z = blockIdx.z;                              // 0=lidar, 1=radar

    const float* f = z ? rf : lf;
    const int*   w = z ? wr : wl;

    int4 v = *(const int4*)(w + (size_t)b*NS + s);
    int wa[4] = {v.x, v.y, v.z, v.w};

    float* o1 = (z ? out_r : out_l) + (size_t)b*CC*NS + s;
    float* o2 = out_cat + (size_t)b*256*NS + (size_t)(z ? 128 : 0)*NS + s;

    #pragma unroll 2
    for (int g = 0; g < 16; ++g) {
        int c = g * 4;
        f4v x0 = ld4(wa[0], f, c);
        f4v x1 = ld4(wa[1], f, c);
        f4v x2 = ld4(wa[2], f, c);
        f4v x3 = ld4(wa[3], f, c);
        #pragma unroll
        for (int k = 0; k < 4; ++k) {
            size_t cs = (size_t)(c + k) * NS;
            nt_store4(o1 + cs, x0[k], x1[k], x2[k], x3[k]);
            nt_store4(o2 + cs, x0[k], x1[k], x2[k], x3[k]);
        }
    }
}

// ---------------------------------------------------------------------------
// Pass 2b: cen grids (lidar_cen, radar_cen). Thread owns 4 consecutive output
// cells x all 64 channels of ONE source; 2x2 max-pool of sub-cell winner rows
// (max with 0 == reference's pool over the zero-init grid). 16 winner regs +
// one gather group live. Writes the cat section only.
// ---------------------------------------------------------------------------
__global__ void __launch_bounds__(256)
dense_cen(const float* __restrict__ lcf, const float* __restrict__ rcf,
          const int* __restrict__ wlc, const int* __restrict__ wrc,
          float* __restrict__ out_cat)
{
    int s = (blockIdx.x * 256 + threadIdx.x) * 4;   // first of 4 output cells
    int b = blockIdx.y;
    int z = blockIdx.z;                              // 0=lidar_cen, 1=radar_cen

    const float* f = z ? rcf : lcf;
    const int*   w = z ? wrc : wlc;

    // cen sub-cell winners: rows 2*py, 2*py+1, cols 2*px .. 2*px+7
    int py = s / NX, px = s - py * NX;
    int y0 = py * 2, x0 = px * 2;                    // x0 is 8-aligned
    const int* wb = w + (size_t)b * NSC;
    int4 t0 = *(const int4*)(wb + (size_t)y0*NXC + x0);
    int4 t1 = *(const int4*)(wb + (size_t)y0*NXC + x0 + 4);
    int4 b0 = *(const int4*)(wb + (size_t)(y0+1)*NXC + x0);
    int4 b1 = *(const int4*)(wb + (size_t)(y0+1)*NXC + x0 + 4);
    int wt[8] = {t0.x, t0.y, t0.z, t0.w, t1.x, t1.y, t1.z, t1.w};
    int wbm[8] = {b0.x, b0.y, b0.z, b0.w, b1.x, b1.y, b1.z, b1.w};

    float* o2 = out_cat + (size_t)b*256*NS + (size_t)(z ? 192 : 64)*NS + s;

    #pragma unroll 1
    for (int g = 0; g < 16; ++g) {
        int c = g * 4;
        f4v a[4];
        #pragma unroll
        for (int j = 0; j < 4; ++j) {
            f4v m = ld4(wt[2*j], f, c);
            m = max4(m, ld4(wt[2*j+1],  f, c));
            m = max4(m, ld4(wbm[2*j],   f, c));
            m = max4(m, ld4(wbm[2*j+1], f, c));
            a[j] = m;
        }
        #pragma unroll
        for (int k = 0; k < 4; ++k) {
            size_t cs = (size_t)(c + k) * NS;
            nt_store4(o2 + cs, a[0][k], a[1][k], a[2][k], a[3][k]);
        }
    }
}

extern "C" void kernel_launch(void* const* d_in, const int* in_sizes, int n_in,
                              void* d_out, int out_size, void* d_ws, size_t ws_size,
                              hipStream_t stream) {
    // Inputs per setup_inputs() order
    const float* rc_feat   = (const float*)d_in[0];  // radar_cen
    const int*   rc_coords = (const int*)  d_in[1];
    const float* lc_feat   = (const float*)d_in[2];  // lidar_cen
    const int*   lc_coords = (const int*)  d_in[3];
    const float* l_feat    = (const float*)d_in[4];  // lidar
    const int*   l_coords  = (const int*)  d_in[5];
    const float* r_feat    = (const float*)d_in[6];  // radar
    const int*   r_coords  = (const int*)  d_in[7];

    int P_rc = in_sizes[0] / CC;
    int P_lc = in_sizes[2] / CC;
    int P_l  = in_sizes[4] / CC;
    int P_r  = in_sizes[6] / CC;

    // Output layout (flat, in return order): lidar, radar, cat
    float* out_lidar = (float*)d_out;                 // [2,64,480,480]
    float* out_radar = out_lidar + (size_t)BB*CC*NS;  // [2,64,480,480]
    float* out_cat   = out_radar + (size_t)BB*CC*NS;  // [2,256,480,480]

    // Workspace: winner grids only, init -1 (memset 0xFF)
    int* w_l  = (int*)d_ws;          // [B*NS]
    int* w_r  = w_l  + BB*NS;        // [B*NS]
    int* w_lc = w_r  + BB*NS;        // [B*NSC]
    int* w_rc = w_lc + BB*NSC;       // [B*NSC]
    size_t ws_bytes = (size_t)(2*BB*NS + 2*BB*NSC) * sizeof(int);  // ~18.4 MB

    hipMemsetAsync(d_ws, 0xFF, ws_bytes, stream);

    // Pass 1: winner resolution, one dispatch for all four sources
    SrcDesc s_l  = { l_coords,  w_l,  P_l,  NX,  NS  };
    SrcDesc s_r  = { r_coords,  w_r,  P_r,  NX,  NS  };
    SrcDesc s_lc = { lc_coords, w_lc, P_lc, NXC, NSC };
    SrcDesc s_rc = { rc_coords, w_rc, P_rc, NXC, NSC };
    int maxP = max(max(P_l, P_r), max(P_lc, P_rc));
    dim3 wgrid((maxP + 255) / 256, 4);
    scatter_winner4<<<wgrid, 256, 0, stream>>>(s_l, s_r, s_lc, s_rc);

    // Pass 2: dense gather-write, split by source for low VGPR / high occupancy
    dim3 grid(NS / (256 * 4), BB, 2);
    dense_direct<<<grid, 256, 0, stream>>>(l_feat, r_feat, w_l, w_r,
                                           out_lidar, out_radar, out_cat);
    dense_cen<<<grid, 256, 0, stream>>>(lc_feat, rc_feat, w_lc, w_rc, out_cat);
}